// Round 1
// baseline (586.086 us; speedup 1.0000x reference)
//
#include <hip/hip_runtime.h>
#include <hip/hip_bf16.h>

#define B_    8
#define CIN_  256
#define COUT_ 256
#define CINFO_ 256
#define R_    2
#define L_    32768

typedef __attribute__((ext_vector_type(8))) short bf16x8;
typedef __attribute__((ext_vector_type(4))) float f32x4;

static __device__ __forceinline__ short f2bf(float v) {
    __hip_bfloat16 h = __float2bfloat16(v);
    return __builtin_bit_cast(short, h);
}

// Kernel 1: fold the rank-2 LoRA update into an effective per-batch weight
// matrix M_b[o][c] = W_main[o][c] + sum_r a_in[b][c][r]*a_out[b][r][o], bf16.
// a_in[b][c][r]  = dot(W_ain [c*R + r, :],    g[b])   (reshape (-1, CIN, R))
// a_out[b][r][o] = dot(W_aout[r*COUT + o, :], g[b])   (reshape (-1, R, COUT))
__global__ void build_m_kernel(const float* __restrict__ g_out,
                               const float* __restrict__ W_main,
                               const float* __restrict__ W_ain,
                               const float* __restrict__ W_aout,
                               __hip_bfloat16* __restrict__ Mout) {
    const int b = blockIdx.x;
    const int t = threadIdx.x;  // 256 threads

    __shared__ float g_s[CINFO_];
    __shared__ float a_in_s[CIN_ * R_];    // [c*R + r]
    __shared__ float a_out_s[R_ * COUT_];  // [r*COUT + o]

    g_s[t] = g_out[b * CINFO_ + t];
    __syncthreads();

    for (int k = t; k < CIN_ * R_; k += 256) {
        const float* w = W_ain + (size_t)k * CINFO_;
        float s = 0.f;
        #pragma unroll 4
        for (int i = 0; i < CINFO_; ++i) s += w[i] * g_s[i];
        a_in_s[k] = s;
    }
    for (int k = t; k < R_ * COUT_; k += 256) {
        const float* w = W_aout + (size_t)k * CINFO_;
        float s = 0.f;
        #pragma unroll 4
        for (int i = 0; i < CINFO_; ++i) s += w[i] * g_s[i];
        a_out_s[k] = s;
    }
    __syncthreads();

    // M rows: consecutive threads -> consecutive c within a row (coalesced).
    for (int idx = t; idx < COUT_ * CIN_; idx += 256) {
        const int o = idx >> 8;
        const int c = idx & 255;
        float m = W_main[idx];
        #pragma unroll
        for (int r = 0; r < R_; ++r)
            m += a_in_s[c * R_ + r] * a_out_s[r * COUT_ + o];
        Mout[(size_t)b * COUT_ * CIN_ + idx] = __float2bfloat16(m);
    }
}

// Kernel 2: out[b] = M_b @ x[b] + bias.  Block = 4 waves; wave w owns output
// channels [64w, 64w+64).  Per block: l-strip of 128, processed as 8 subtiles
// of 16 columns.  A-fragments (M) live in registers for the whole block.
// B-fragments (x) are built by per-lane scalar f32 loads directly from global
// (each wave instruction = 4 x 64B contiguous segments -> coalesced), f32->bf16
// converted in registers.  No LDS, no barriers in the main loop.
__global__ __launch_bounds__(256, 2)
void lora_gemm_kernel(const float* __restrict__ x,
                      const float* __restrict__ b_main,
                      const __hip_bfloat16* __restrict__ M,
                      float* __restrict__ out) {
    const int b    = blockIdx.y;
    const int l0   = blockIdx.x * 128;
    const int wave = threadIdx.x >> 6;
    const int lane = threadIdx.x & 63;
    const int o_base = wave * 64;
    const int row_a  = lane & 15;   // A row / B col / D col within fragment
    const int kgrp   = lane >> 4;   // k-group: k = kc*32 + kgrp*8 + j

    // ---- A fragments: M rows [o_base, o_base+64), all K=256. 128 VGPRs. ----
    bf16x8 afrag[4][8];
    const short* Mp = (const short*)M + (size_t)b * COUT_ * CIN_;
    #pragma unroll
    for (int m = 0; m < 4; ++m) {
        const int o = o_base + m * 16 + row_a;
        #pragma unroll
        for (int kc = 0; kc < 8; ++kc) {
            const int c = kc * 32 + kgrp * 8;
            afrag[m][kc] = *(const bf16x8*)(Mp + (size_t)o * CIN_ + c);
        }
    }

    // ---- bias for D rows this lane owns: row = o_base + m*16 + kgrp*4 + j ----
    float bias[4][4];
    #pragma unroll
    for (int m = 0; m < 4; ++m)
        #pragma unroll
        for (int j = 0; j < 4; ++j)
            bias[m][j] = b_main[o_base + m * 16 + kgrp * 4 + j];

    const float* xb = x   + (size_t)b * CIN_  * L_;
    float*       ob = out + (size_t)b * COUT_ * L_;

    #pragma unroll 1
    for (int ls = 0; ls < 8; ++ls) {
        const int l = l0 + ls * 16 + row_a;

        // B fragments: x[c = kc*32 + kgrp*8 + j][l], 8 consecutive c per lane.
        bf16x8 bfrag[8];
        #pragma unroll
        for (int kc = 0; kc < 8; ++kc) {
            const int cbase = kc * 32 + kgrp * 8;
            float v[8];
            #pragma unroll
            for (int j = 0; j < 8; ++j)
                v[j] = xb[(size_t)(cbase + j) * L_ + l];
            bf16x8 f;
            #pragma unroll
            for (int j = 0; j < 8; ++j)
                f[j] = f2bf(v[j]);
            bfrag[kc] = f;
        }

        f32x4 acc[4];
        #pragma unroll
        for (int m = 0; m < 4; ++m) {
            f32x4 a;
            a[0] = bias[m][0]; a[1] = bias[m][1];
            a[2] = bias[m][2]; a[3] = bias[m][3];
            acc[m] = a;
        }

        #pragma unroll
        for (int kc = 0; kc < 8; ++kc)
            #pragma unroll
            for (int m = 0; m < 4; ++m)
                acc[m] = __builtin_amdgcn_mfma_f32_16x16x32_bf16(
                    afrag[m][kc], bfrag[kc], acc[m], 0, 0, 0);

        // D: col = lane&15 (=l), row = o_base + m*16 + kgrp*4 + j
        #pragma unroll
        for (int m = 0; m < 4; ++m)
            #pragma unroll
            for (int j = 0; j < 4; ++j)
                ob[(size_t)(o_base + m * 16 + kgrp * 4 + j) * L_ + l] = acc[m][j];
    }
}

extern "C" void kernel_launch(void* const* d_in, const int* in_sizes, int n_in,
                              void* d_out, int out_size, void* d_ws, size_t ws_size,
                              hipStream_t stream) {
    const float* x      = (const float*)d_in[0];
    const float* g_out  = (const float*)d_in[1];
    const float* W_main = (const float*)d_in[2];
    const float* b_main = (const float*)d_in[3];
    const float* W_ain  = (const float*)d_in[4];
    const float* W_aout = (const float*)d_in[5];
    float* out = (float*)d_out;

    __hip_bfloat16* M = (__hip_bfloat16*)d_ws;  // 8*256*256*2 = 1 MB scratch

    build_m_kernel<<<dim3(B_), dim3(256), 0, stream>>>(g_out, W_main, W_ain, W_aout, M);
    lora_gemm_kernel<<<dim3(L_ / 128, B_), dim3(256), 0, stream>>>(x, b_main, M, out);
}